// Round 1
// 14621.286 us; speedup vs baseline: 1.0835x; 1.0835x over previous
//
#include <hip/hip_runtime.h>
#include <hip/hip_bf16.h>

typedef __attribute__((ext_vector_type(8))) short bf16x8;
typedef __attribute__((ext_vector_type(4))) float f32x4;

#define NB 512      // batch
#define NT 128      // timesteps
#define NC 66       // input channels
#define NH 512      // hidden
#define NW 10       // window
#define CP 96       // padded C (3 k-stages of 32)
#define BM 32       // batch tile
#define BJ 64       // j (h-dim) tile
#define NWG 256
#define NTHR 256
#define G3 1536     // 3*NH
#define NKS_H 16    // NH/32 k-stages
#define NKS_X 3     // CP/32 k-stages

struct Params {
  const float *x, *Wih0, *Whh0, *bih0, *bhh0, *Wih1, *Whh1, *bih1, *bhh1, *tw, *tb, *sw, *sb;
  float *out;
  unsigned *barL, *barG;
  __hip_bfloat16 *Wih0h, *Wih0l;     // layer0 input weights, swizzled split, nks=3
  __hip_bfloat16 *Wch, *Wcl;         // composed Wc = Wih0 @ sw, swizzled split, nks=16
  __hip_bfloat16 *Whh0H, *Whh0L;     // swizzled split, nks=16
  __hip_bfloat16 *Wih1H, *Wih1L;
  __hip_bfloat16 *Whh1H, *Whh1L;
  float *cb;                         // cb = Wih0 @ sb  [G3]
  float *h0, *h1, *tvec;
  __hip_bfloat16 *winb;              // sliding window, bf16, WG-private tiles
};

__device__ __forceinline__ float sigmoidf_(float x) { return 1.f / (1.f + __expf(-x)); }
__device__ __forceinline__ float tanhf_(float x) {
  float e = __expf(2.f * x);
  return (e - 1.f) / (e + 1.f);
}
__device__ __forceinline__ void split2(float v, __hip_bfloat16& h, __hip_bfloat16& l) {
  h = __float2bfloat16(v);
  l = __float2bfloat16(v - __bfloat162float(h));
}
__device__ __forceinline__ unsigned short bfbits(__hip_bfloat16 h) { return *(unsigned short*)&h; }
__device__ __forceinline__ void splitpack4(float4 v, ushort4& ph, ushort4& pl) {
  __hip_bfloat16 h, l;
  split2(v.x, h, l); ph.x = bfbits(h); pl.x = bfbits(l);
  split2(v.y, h, l); ph.y = bfbits(h); pl.y = bfbits(l);
  split2(v.z, h, l); ph.z = bfbits(h); pl.z = bfbits(l);
  split2(v.w, h, l); ph.w = bfbits(h); pl.w = bfbits(l);
}

// device-coherent (L1-bypass) loads for cross-WG activation data
__device__ __forceinline__ float4 cload4(const float* p) {
  unsigned long long a = __hip_atomic_load((const unsigned long long*)p,       __ATOMIC_RELAXED, __HIP_MEMORY_SCOPE_AGENT);
  unsigned long long b = __hip_atomic_load(((const unsigned long long*)p) + 1, __ATOMIC_RELAXED, __HIP_MEMORY_SCOPE_AGENT);
  float4 r;
  ((unsigned long long*)&r)[0] = a;
  ((unsigned long long*)&r)[1] = b;
  return r;
}

// hierarchical fence-light grid barrier (round-4, verified) -- UNCHANGED
__device__ __forceinline__ void gbar(unsigned* barL, unsigned* barG, unsigned& phase,
                                     int tid, int grp) {
  __syncthreads();
  ++phase;
  if (tid == 0) {
    unsigned old = __hip_atomic_fetch_add(&barL[grp * 32], 1u, __ATOMIC_RELEASE,
                                          __HIP_MEMORY_SCOPE_AGENT);
    if (old == phase * 32 - 1)
      __hip_atomic_fetch_add(barG, 1u, __ATOMIC_RELAXED, __HIP_MEMORY_SCOPE_AGENT);
    while (__hip_atomic_load(barG, __ATOMIC_RELAXED, __HIP_MEMORY_SCOPE_AGENT) < phase)
      __builtin_amdgcn_s_sleep(2);
  }
  __syncthreads();
  asm volatile("" ::: "memory");
}

#define AM_X 0
#define AM_H 2

__device__ __forceinline__ void zacc(f32x4 acc[2][4]) {
#pragma unroll
  for (int i = 0; i < 2; ++i)
#pragma unroll
    for (int g = 0; g < 4; ++g) {
      acc[i][g][0] = 0.f; acc[i][g][1] = 0.f; acc[i][g][2] = 0.f; acc[i][g][3] = 0.f;
    }
}

// Fragment-direct (BM x 3*BJ) gate tile: B fragments loaded straight from
// pre-swizzled split-bf16 global weights (coalesced 1KB dwordx4 per frag set),
// A fragments loaded per-lane; 2-deep register pipeline; NO LDS, NO syncthreads.
// Swizzled layout: elem((jb,ks,lane,e)) = ((jb*nks + ks)*64 + lane)*8 + e
//   holds W[jb*16 + (lane&15)][ks*32 + (lane>>4)*8 + e].
template <int G2, int AMODE>
__device__ __forceinline__ void gemm_frag(
    f32x4 acc[2][4],
    const __hip_bfloat16* __restrict__ WH, const __hip_bfloat16* __restrict__ WL,
    const int nks,
    const float* __restrict__ A, int tstep, int b0, int j0, int tid)
{
  const int wv = tid >> 6, lane = tid & 63, quad = lane >> 4, l15 = lane & 15;
  const int ms = wv & 1, jh = wv >> 1;
  const int arow = b0 + ms * 16 + l15;

  unsigned boff[6];
#pragma unroll
  for (int c = 0; c < 3; ++c)
#pragma unroll
    for (int jl = 0; jl < 2; ++jl) {
      const int jb = c * 32 + (j0 >> 4) + jh * 2 + jl;   // row-block of 16
      boff[c * 2 + jl] = (unsigned)((jb * nks) * 64 + lane) * 8u;
    }

  const float* arp = (AMODE == AM_X)
      ? A + ((size_t)arow * NT + tstep) * NC
      : A + (size_t)arow * NH + (quad << 3);

  uint4 bh0[6], bl0[6], bh1[6], bl1[6];
  float a0[8], a1[8];

  auto loadB = [&](uint4 (&bh)[6], uint4 (&bl)[6], int st) {
    const unsigned so = (unsigned)st * 512u;   // 64 lanes * 8 elems per stage-block
#pragma unroll
    for (int f = 0; f < 6; ++f) {
      bh[f] = *(const uint4*)(WH + boff[f] + so);
      bl[f] = *(const uint4*)(WL + boff[f] + so);
    }
  };
  auto loadAfr = [&](float (&a)[8], int st) {
    if (AMODE == AM_X) {
      const int k0 = st * 32 + (quad << 3);
#pragma unroll
      for (int e = 0; e < 8; ++e) a[e] = (k0 + e < NC) ? arp[k0 + e] : 0.f;
    } else {
      const float4 v0 = cload4(arp + st * 32);
      const float4 v1 = cload4(arp + st * 32 + 4);
      a[0] = v0.x; a[1] = v0.y; a[2] = v0.z; a[3] = v0.w;
      a[4] = v1.x; a[5] = v1.y; a[6] = v1.z; a[7] = v1.w;
    }
  };
  auto comp = [&](const uint4 (&bh)[6], const uint4 (&bl)[6], const float (&a)[8]) {
    float4 v0, v1;
    v0.x = a[0]; v0.y = a[1]; v0.z = a[2]; v0.w = a[3];
    v1.x = a[4]; v1.y = a[5]; v1.z = a[6]; v1.w = a[7];
    ushort4 ph0, pl0, ph1, pl1;
    splitpack4(v0, ph0, pl0);
    splitpack4(v1, ph1, pl1);
    bf16x8 ah, al;
    ((ushort4*)&ah)[0] = ph0; ((ushort4*)&ah)[1] = ph1;
    ((ushort4*)&al)[0] = pl0; ((ushort4*)&al)[1] = pl1;
#pragma unroll
    for (int jl = 0; jl < 2; ++jl)
#pragma unroll
      for (int c = 0; c < 3; ++c) {
        const int f = c * 2 + jl;
        const int g = (c == 2) ? G2 : c;
        const bf16x8 vbh = *(const bf16x8*)&bh[f];
        const bf16x8 vbl = *(const bf16x8*)&bl[f];
        acc[jl][g] = __builtin_amdgcn_mfma_f32_16x16x32_bf16(ah, vbh, acc[jl][g], 0, 0, 0);
        acc[jl][g] = __builtin_amdgcn_mfma_f32_16x16x32_bf16(al, vbh, acc[jl][g], 0, 0, 0);
        acc[jl][g] = __builtin_amdgcn_mfma_f32_16x16x32_bf16(ah, vbl, acc[jl][g], 0, 0, 0);
      }
  };

  loadB(bh0, bl0, 0);
  loadAfr(a0, 0);
  if (nks > 1) { loadB(bh1, bl1, 1); loadAfr(a1, 1); }
  for (int st = 0; st < nks; st += 2) {
    comp(bh0, bl0, a0);
    if (st + 2 < nks) { loadB(bh0, bl0, st + 2); loadAfr(a0, st + 2); }
    if (st + 1 < nks) {
      comp(bh1, bl1, a1);
      if (st + 3 < nks) { loadB(bh1, bl1, st + 3); loadAfr(a1, st + 3); }
    }
  }
}

// GRU elementwise; hold/hnew/win tiles are WG-private -> plain loads/stores.
__device__ __forceinline__ void ew_gru(
    f32x4 acc[2][4],
    const float* __restrict__ bi, const float* __restrict__ bh,
    const float* __restrict__ hold, float* __restrict__ hnew,
    int b0, int j0, int tid, __hip_bfloat16* win, int slot)
{
  const int wv = tid >> 6, lane = tid & 63, quad = lane >> 4, l15 = lane & 15;
  const int ms = wv & 1, jh = wv >> 1;
#pragma unroll
  for (int jlf = 0; jlf < 2; ++jlf) {
    const int j = j0 + jh * 32 + jlf * 16 + l15;
    const float br = bi[j] + bh[j];
    const float bz = bi[NH + j] + bh[NH + j];
    const float bni = bi[2 * NH + j];
    const float bnh = bh[2 * NH + j];
#pragma unroll
    for (int rg = 0; rg < 4; ++rg) {
      const int b = b0 + ms * 16 + quad * 4 + rg;
      const float r = sigmoidf_(acc[jlf][0][rg] + br);
      const float z = sigmoidf_(acc[jlf][1][rg] + bz);
      const float n = tanhf_(acc[jlf][2][rg] + bni + r * (acc[jlf][3][rg] + bnh));
      const float h = hold[(size_t)b * NH + j];
      const float hn = (1.f - z) * n + z * h;
      hnew[(size_t)b * NH + j] = hn;
      if (win) win[((size_t)b * NW + slot) * NH + j] = __float2bfloat16(hn);
    }
  }
}

// decoder layer-1 EW: acc already holds input-proj + hidden-proj sums
// (r,z in acc[0],[1]; nI in acc[2]; nH in acc[3]). h1/window/tvec tiles private.
__device__ __forceinline__ void ew_dec1(
    f32x4 acc[2][4], const Params& P, float* __restrict__ h1p,
    int b0, int j0, int tid, int s)
{
  const int wv = tid >> 6, lane = tid & 63, quad = lane >> 4, l15 = lane & 15;
  const int ms = wv & 1, jh = wv >> 1;
  const int slot = s % NW;
  float twv[NW];
#pragma unroll
  for (int k = 0; k < NW; ++k) {
    int idx = k - slot - 1; if (idx < 0) idx += NW;
    twv[k] = P.tw[idx];
  }
  const float tw9 = P.tw[NW - 1];
  const float tb0 = P.tb[0];
#pragma unroll
  for (int jlf = 0; jlf < 2; ++jlf) {
    const int j = j0 + jh * 32 + jlf * 16 + l15;
    const float br = P.bih1[j] + P.bhh1[j];
    const float bz = P.bih1[NH + j] + P.bhh1[NH + j];
    const float bni = P.bih1[2 * NH + j];
    const float bnh = P.bhh1[2 * NH + j];
#pragma unroll
    for (int rg = 0; rg < 4; ++rg) {
      const int b = b0 + ms * 16 + quad * 4 + rg;
      const float r = sigmoidf_(acc[jlf][0][rg] + br);
      const float z = sigmoidf_(acc[jlf][1][rg] + bz);
      const float n = tanhf_(acc[jlf][2][rg] + bni + r * (acc[jlf][3][rg] + bnh));
      const float h = h1p[(size_t)b * NH + j];
      const float hn = (1.f - z) * n + z * h;
      h1p[(size_t)b * NH + j] = hn;
      __hip_bfloat16* wrow = P.winb + (size_t)b * NW * NH + j;
      wrow[(size_t)slot * NH] = __float2bfloat16(hn);
      float ts = tb0 + hn * tw9;
#pragma unroll
      for (int k = 0; k < NW; ++k) {
        if (k == slot) continue;
        ts += __bfloat162float(wrow[(size_t)k * NH]) * twv[k];
      }
      P.tvec[(size_t)b * NH + j] = ts;
    }
  }
}

__global__ __launch_bounds__(NTHR) void rnn_kernel(Params P) {
  __shared__ __align__(16) float tl[4 * NH];
  const int tid = threadIdx.x;
  const int wg = blockIdx.x;
  const int grp = wg & 7;
  const size_t gid = (size_t)wg * NTHR + tid;
  const size_t GT = (size_t)NWG * NTHR;
  unsigned phase = 0;
  const int wv = tid >> 6, lane = tid & 63, l15 = lane & 15;
  const int jh = wv >> 1;

  // ---- init: build swizzled split-bf16 weights ----
  // Wih0, nks=3, K padded to CP with zeros
  for (size_t f = gid; f < (size_t)G3 * CP / 8; f += GT) {
    const int ln = (int)(f & 63), blk = (int)(f >> 6);
    const int ks = blk % NKS_X, jb = blk / NKS_X;
    const int r = jb * 16 + (ln & 15);
    const int k0 = ks * 32 + ((ln >> 4) << 3);
#pragma unroll
    for (int e = 0; e < 8; ++e) {
      const int k = k0 + e;
      split2(k < NC ? P.Wih0[(size_t)r * NC + k] : 0.f,
             P.Wih0h[f * 8 + e], P.Wih0l[f * 8 + e]);
    }
  }
  // Whh0 / Wih1 / Whh1, nks=16
  {
    const float* srcs[3] = { P.Whh0, P.Wih1, P.Whh1 };
    __hip_bfloat16* dhs[3] = { P.Whh0H, P.Wih1H, P.Whh1H };
    __hip_bfloat16* dls[3] = { P.Whh0L, P.Wih1L, P.Whh1L };
#pragma unroll
    for (int m = 0; m < 3; ++m) {
      const float* __restrict__ W = srcs[m];
      __hip_bfloat16* __restrict__ DH = dhs[m];
      __hip_bfloat16* __restrict__ DL = dls[m];
      for (size_t f = gid; f < (size_t)G3 * NH / 8; f += GT) {
        const int ln = (int)(f & 63), blk = (int)(f >> 6);
        const int ks = blk & 15, jb = blk >> 4;
        const int r = jb * 16 + (ln & 15);
        const int k0 = ks * 32 + ((ln >> 4) << 3);
        const float* src = W + (size_t)r * NH + k0;
        ushort4 h0v, l0v, h1v, l1v;
        splitpack4(*(const float4*)(src), h0v, l0v);
        splitpack4(*(const float4*)(src + 4), h1v, l1v);
        *(ushort4*)(DH + f * 8)     = h0v;
        *(ushort4*)(DH + f * 8 + 4) = h1v;
        *(ushort4*)(DL + f * 8)     = l0v;
        *(ushort4*)(DL + f * 8 + 4) = l1v;
      }
    }
  }
  // Wc = Wih0 @ sw (fp32 compose, swizzled split-bf16 store), nks=16
  for (size_t f = gid; f < (size_t)G3 * NH / 8; f += GT) {
    const int ln = (int)(f & 63), blk = (int)(f >> 6);
    const int ks = blk & 15, jb = blk >> 4;
    const int r = jb * 16 + (ln & 15);
    const int k0 = ks * 32 + ((ln >> 4) << 3);
    float s[8] = {0.f, 0.f, 0.f, 0.f, 0.f, 0.f, 0.f, 0.f};
    for (int c = 0; c < NC; ++c) {
      const float a = P.Wih0[(size_t)r * NC + c];
      const float4 w0 = *(const float4*)(P.sw + (size_t)c * NH + k0);
      const float4 w1 = *(const float4*)(P.sw + (size_t)c * NH + k0 + 4);
      s[0] += a * w0.x; s[1] += a * w0.y; s[2] += a * w0.z; s[3] += a * w0.w;
      s[4] += a * w1.x; s[5] += a * w1.y; s[6] += a * w1.z; s[7] += a * w1.w;
    }
#pragma unroll
    for (int e = 0; e < 8; ++e) split2(s[e], P.Wch[f * 8 + e], P.Wcl[f * 8 + e]);
  }
  // cb = Wih0 @ sb
  for (size_t i = gid; i < (size_t)G3; i += GT) {
    float a = 0.f;
    for (int c = 0; c < NC; ++c) a += P.Wih0[i * NC + c] * P.sb[c];
    P.cb[i] = a;
  }
  for (size_t i = gid; i < (size_t)2 * NB * NH; i += GT) { P.h0[i] = 0.f; P.h1[i] = 0.f; }
  gbar(P.barL, P.barG, phase, tid, grp);

  const bool isL1 = wg >= 128;
  const int tile = wg & 127;
  const int b0 = (tile >> 3) * BM;
  const int j0 = (tile & 7) * BJ;

  float G[2][3][4];   // running input-projection gates (decoder), filled at encoder tail

  // ---- encoder: pipelined L0/L1, one barrier per iteration; t==128: G init ----
  for (int t = 0; t <= NT; ++t) {
    const int cur = t & 1;
    float* h0c = P.h0 + (size_t)cur * NB * NH;
    float* h0n = P.h0 + (size_t)(cur ^ 1) * NB * NH;
    float* h1c = P.h1 + (size_t)cur * NB * NH;
    float* h1n = P.h1 + (size_t)(cur ^ 1) * NB * NH;
    f32x4 acc[2][4];
    if (!isL1) {
      if (t < NT) {
        zacc(acc);
        gemm_frag<2, AM_X>(acc, P.Wih0h, P.Wih0l, NKS_X, P.x, t, b0, j0, tid);
        gemm_frag<3, AM_H>(acc, P.Whh0H, P.Whh0L, NKS_H, h0c, 0, b0, j0, tid);
        ew_gru(acc, P.bih0, P.bhh0, h0c, h0n, b0, j0, tid, nullptr, 0);
      } else {
        // G_0 = x[:,127,:] @ Wih0^T
        zacc(acc);
        gemm_frag<2, AM_X>(acc, P.Wih0h, P.Wih0l, NKS_X, P.x, NT - 1, b0, j0, tid);
#pragma unroll
        for (int jlf = 0; jlf < 2; ++jlf)
#pragma unroll
          for (int c = 0; c < 3; ++c)
#pragma unroll
            for (int rg = 0; rg < 4; ++rg) G[jlf][c][rg] = acc[jlf][c][rg];
      }
    } else {
      if (t >= 1) {
        zacc(acc);
        gemm_frag<2, AM_H>(acc, P.Wih1H, P.Wih1L, NKS_H, h0c, 0, b0, j0, tid);
        gemm_frag<3, AM_H>(acc, P.Whh1H, P.Whh1L, NKS_H, h1c, 0, b0, j0, tid);
        ew_gru(acc, P.bih1, P.bhh1, h1c, h1n, b0, j0, tid,
               (t >= 119) ? P.winb : nullptr, t - 119);
      }
    }
    gbar(P.barL, P.barG, phase, tid, grp);
  }

  int d0 = 0;
  float* h1p = P.h1 + (size_t)NB * NH;

  // decoder-only per-thread state
  float cbr[2][3];
  float Freg[2];
  if (!isL1) {
#pragma unroll
    for (int jlf = 0; jlf < 2; ++jlf)
#pragma unroll
      for (int c = 0; c < 3; ++c)
        cbr[jlf][c] = P.cb[c * NH + j0 + jh * 32 + jlf * 16 + l15];
#pragma unroll
    for (int v = 0; v < 2; ++v) {
      const int t2 = tid + v * NTHR;
      if (t2 < 4 * NC) {
        const int bl = t2 / NC, c = t2 - bl * NC, b = wg * 4 + bl;
        Freg[v] = P.x[((size_t)b * NT + (NT - 1)) * NC + c];
      }
    }
  }

  auto frame_out = [&](int sout) {   // F += tvec_sout @ sw^T + sb; write out[:, sout, :]
    const float* tvb = P.tvec + (size_t)wg * 4 * NH;
    *(float4*)&tl[tid * 8] = cload4(tvb + tid * 8);
    *(float4*)&tl[tid * 8 + 4] = cload4(tvb + tid * 8 + 4);
    __syncthreads();
#pragma unroll
    for (int v = 0; v < 2; ++v) {
      const int t2 = tid + v * NTHR;
      if (t2 < 4 * NC) {
        const int bl = t2 / NC, c = t2 - bl * NC, b = wg * 4 + bl;
        float f = Freg[v] + P.sb[c];
        const float4* swr = (const float4*)(P.sw + (size_t)c * NH);
        const float4* tr = (const float4*)(tl + bl * NH);
#pragma unroll 8
        for (int h4 = 0; h4 < NH / 4; ++h4) {
          float4 tv = tr[h4], wv4 = swr[h4];
          f += tv.x * wv4.x + tv.y * wv4.y + tv.z * wv4.z + tv.w * wv4.w;
        }
        Freg[v] = f;
        P.out[((size_t)b * NT + sout) * NC + c] = f;
      }
    }
    __syncthreads();
  };

  // ---- decoder: 2 barriers per step ----
  for (int s = 0; s < NT; ++s) {
    float* h0c = P.h0 + (size_t)d0 * NB * NH;
    float* h0n = P.h0 + (size_t)(d0 ^ 1) * NB * NH;
    f32x4 acc[2][4];
    if (!isL1) {
      if (s >= 1) frame_out(s - 1);          // pipelined frame output (uses tvec_{s-1})
      zacc(acc);
      if (s >= 1)
        gemm_frag<2, AM_H>(acc, P.Wch, P.Wcl, NKS_H, P.tvec, 0, b0, j0, tid);
#pragma unroll
      for (int jlf = 0; jlf < 2; ++jlf)
#pragma unroll
        for (int c = 0; c < 3; ++c)
#pragma unroll
          for (int rg = 0; rg < 4; ++rg) {
            float g = G[jlf][c][rg] + acc[jlf][c][rg] + (s >= 1 ? cbr[jlf][c] : 0.f);
            G[jlf][c][rg] = g;
            acc[jlf][c][rg] = g;             // acc[.][3] stays 0 for Whh0's nH
          }
      gemm_frag<3, AM_H>(acc, P.Whh0H, P.Whh0L, NKS_H, h0c, 0, b0, j0, tid);
      ew_gru(acc, P.bih0, P.bhh0, h0c, h0n, b0, j0, tid, nullptr, 0);
    } else {
      zacc(acc);
      gemm_frag<3, AM_H>(acc, P.Whh1H, P.Whh1L, NKS_H, h1p, 0, b0, j0, tid);
    }
    gbar(P.barL, P.barG, phase, tid, grp);
    if (isL1) {
      gemm_frag<2, AM_H>(acc, P.Wih1H, P.Wih1L, NKS_H, h0n, 0, b0, j0, tid);
      ew_dec1(acc, P, h1p, b0, j0, tid, s);
    }
    gbar(P.barL, P.barG, phase, tid, grp);
    d0 ^= 1;
  }
  if (!isL1) frame_out(NT - 1);   // tail: frame for s=127
}

extern "C" void kernel_launch(void* const* d_in, const int* in_sizes, int n_in,
                              void* d_out, int out_size, void* d_ws, size_t ws_size,
                              hipStream_t stream) {
  (void)in_sizes; (void)n_in; (void)out_size; (void)ws_size;
  Params P;
  P.x    = (const float*)d_in[0];
  P.Wih0 = (const float*)d_in[1];
  P.Whh0 = (const float*)d_in[2];
  P.bih0 = (const float*)d_in[3];
  P.bhh0 = (const float*)d_in[4];
  P.Wih1 = (const float*)d_in[5];
  P.Whh1 = (const float*)d_in[6];
  P.bih1 = (const float*)d_in[7];
  P.bhh1 = (const float*)d_in[8];
  P.tw   = (const float*)d_in[9];
  P.tb   = (const float*)d_in[10];
  P.sw   = (const float*)d_in[11];
  P.sb   = (const float*)d_in[12];
  P.out  = (float*)d_out;

  char* w = (char*)d_ws;
  size_t used = 0;
  auto take = [&](size_t bytes) {
    char* p = w + used;
    used += (bytes + 255) & ~(size_t)255;
    return p;
  };
  unsigned* bar = (unsigned*)take(2048);
  P.barL = bar;
  P.barG = bar + 8 * 32;
  P.Wih0h = (__hip_bfloat16*)take((size_t)G3 * CP * 2);
  P.Wih0l = (__hip_bfloat16*)take((size_t)G3 * CP * 2);
  P.Wch   = (__hip_bfloat16*)take((size_t)G3 * NH * 2);
  P.Wcl   = (__hip_bfloat16*)take((size_t)G3 * NH * 2);
  P.Whh0H = (__hip_bfloat16*)take((size_t)G3 * NH * 2);
  P.Whh0L = (__hip_bfloat16*)take((size_t)G3 * NH * 2);
  P.Wih1H = (__hip_bfloat16*)take((size_t)G3 * NH * 2);
  P.Wih1L = (__hip_bfloat16*)take((size_t)G3 * NH * 2);
  P.Whh1H = (__hip_bfloat16*)take((size_t)G3 * NH * 2);
  P.Whh1L = (__hip_bfloat16*)take((size_t)G3 * NH * 2);
  P.cb    = (float*)take((size_t)G3 * 4);
  P.h0    = (float*)take((size_t)2 * NB * NH * 4);
  P.h1    = (float*)take((size_t)2 * NB * NH * 4);
  P.tvec  = (float*)take((size_t)NB * NH * 4);
  P.winb  = (__hip_bfloat16*)take((size_t)NB * NW * NH * 2);

  hipMemsetAsync(d_ws, 0, 2048, stream);
  rnn_kernel<<<dim3(NWG), dim3(NTHR), 0, stream>>>(P);
}